// Round 1
// baseline (429.546 us; speedup 1.0000x reference)
//
#include <hip/hip_runtime.h>

// Cumulative max along axis 0 of a [64, 64, 128, 128] fp32 tensor.
// N = 64 scan steps, inner = 64*128*128 = 1,048,576 elements.
// Memory-bound streaming op: thread t owns inner float4 index t, walks the
// scan axis with a running max in registers. Fully coalesced loads/stores.

#define SCAN_N   64
#define INNER4   (64 * 128 * 128 / 4)   // 262,144 float4 per slice

__global__ __launch_bounds__(256) void cummax_axis0_kernel(
        const float4* __restrict__ x, float4* __restrict__ out) {
    const int i = blockIdx.x * blockDim.x + threadIdx.x;  // inner float4 idx
    if (i >= INNER4) return;

    // n = 0: initialize running max
    float4 m = x[i];
    out[i] = m;

    int off = INNER4 + i;   // max index 64*262144 = 16.7M < 2^31, int is fine
    #pragma unroll 4
    for (int n = 1; n < SCAN_N; ++n, off += INNER4) {
        const float4 v = x[off];
        m.x = fmaxf(m.x, v.x);
        m.y = fmaxf(m.y, v.y);
        m.z = fmaxf(m.z, v.z);
        m.w = fmaxf(m.w, v.w);
        out[off] = m;
    }
}

extern "C" void kernel_launch(void* const* d_in, const int* in_sizes, int n_in,
                              void* d_out, int out_size, void* d_ws, size_t ws_size,
                              hipStream_t stream) {
    const float4* x = (const float4*)d_in[0];
    float4* out = (float4*)d_out;

    const int threads = 256;
    const int blocks = INNER4 / threads;  // 1024
    cummax_axis0_kernel<<<blocks, threads, 0, stream>>>(x, out);
}